// Round 2
// baseline (598.446 us; speedup 1.0000x reference)
//
#include <hip/hip_runtime.h>
#include <math.h>

#define NP 256   // datapoints
#define BB 128   // batch
#define DD 784   // dims
#define HS_MIN 1e-7f
#define LOG_HS_MIN -16.11809565095832f   // log(1e-7)
#define LOG_MB -16.811242831518264f      // log(5e-8) — mask bound in log space
#define NEG_HALF_LOG_2PI -0.9189385332046727f
#define W 16     // householder window
#define NW 49    // 784/16

// ---------------- ndtri (AS241, double) from log_cdf / log_sf ----------------
// Tail branches fed directly with log-probabilities: avoids the 1-p
// cancellation entirely (p near 1 is only representable as log_sf).
__device__ double ndtri_logs(float log_cdf_f, float log_sf_f) {
    double lp = (double)log_cdf_f;
    double ls = (double)log_sf_f;
    double p = exp(lp);
    double q = p - 0.5;
    if (fabs(q) <= 0.425) {
        double r = 0.180625 - q * q;
        double num = (((((((2.5090809287301226727e3 * r + 3.3430575583588128105e4) * r
                         + 6.7265770927008700853e4) * r + 4.5921953931549871457e4) * r
                         + 1.3731693765509461125e4) * r + 1.9715909503065514427e3) * r
                         + 1.3314166789178437745e2) * r + 3.3871328727963666080e0);
        double den = (((((((5.2264952788528545610e3 * r + 2.8729085735721942674e4) * r
                         + 3.9307895800092710610e4) * r + 2.1213794301586595867e4) * r
                         + 5.3941960214247511077e3) * r + 6.8718700749205790830e2) * r
                         + 4.2313330701600911252e1) * r + 1.0);
        return q * num / den;
    }
    // tail: r = sqrt(-log(min(p, 1-p))) computed from the log directly
    double r = (q < 0.0) ? sqrt(-lp) : sqrt(-ls);
    double v;
    if (r <= 5.0) {
        r -= 1.6;
        double num = (((((((7.74545014278341407640e-4 * r + 2.27238449892691845833e-2) * r
                         + 2.41780725177450611770e-1) * r + 1.27045825245236838258e0) * r
                         + 3.64784832476320460504e0) * r + 5.76949722146069140550e0) * r
                         + 4.63033784615654529590e0) * r + 1.42343711074968357734e0);
        double den = (((((((1.05075007164441684324e-9 * r + 5.47593808499534494600e-4) * r
                         + 1.51986665636164571966e-2) * r + 1.48103976427480074590e-1) * r
                         + 6.89767334985100004550e-1) * r + 1.67638483018380384940e0) * r
                         + 2.05319162663775882187e0) * r + 1.0);
        v = num / den;
    } else {
        r -= 5.0;
        double num = (((((((2.01033439929228813265e-7 * r + 2.71155556874348757815e-5) * r
                         + 1.24266094738807843860e-3) * r + 2.65321895265761230930e-2) * r
                         + 2.96560571828504891230e-1) * r + 1.78482653991729133580e0) * r
                         + 5.46378491116411436990e0) * r + 6.65790464350110377720e0);
        double den = (((((((2.04426310338993978564e-15 * r + 1.42151175831644588870e-7) * r
                         + 1.84631831751005468180e-5) * r + 7.86869131145613259100e-4) * r
                         + 1.48753612908506148525e-2) * r + 1.36929880922735805310e-1) * r
                         + 5.99832206555887937690e-1) * r + 1.0);
        v = num / den;
    }
    return (q < 0.0) ? -v : v;
}

// ---------------- block reduce (256 threads) ----------------
__device__ __forceinline__ float blockReduce256(float v, float* red) {
    #pragma unroll
    for (int off = 32; off; off >>= 1) v += __shfl_down(v, off, 64);
    int wv = threadIdx.x >> 6;
    if ((threadIdx.x & 63) == 0) red[wv] = v;
    __syncthreads();
    if (threadIdx.x == 0) red[0] = red[0] + red[1] + red[2] + red[3];
    __syncthreads();
    return red[0];
}

// ---------------- K0: lsew[d] = logsumexp_n kde_weights[n,d] ----------------
__global__ __launch_bounds__(256) void k_lsew(const float* __restrict__ kw,
                                              float* __restrict__ lsew) {
    int d = blockIdx.x * 256 + threadIdx.x;
    if (d >= DD) return;
    float m = -INFINITY, s = 0.f;
    for (int n = 0; n < NP; ++n) {
        float a = kw[n * DD + d];
        float nm = fmaxf(m, a);
        s = s * expf(m - nm) + expf(a - nm);
        m = nm;
    }
    lsew[d] = m + logf(s);
}

// ---------------- K1: per-(n,d) precompute ----------------
__global__ __launch_bounds__(256) void k_prep(const float* __restrict__ kw,
                                              const float* __restrict__ log_hs,
                                              const float* __restrict__ lsew,
                                              float* __restrict__ w,
                                              float* __restrict__ c3,
                                              float* __restrict__ ihs) {
    int n = blockIdx.x;
    for (int d = threadIdx.x; d < DD; d += 256) {
        int idx = n * DD + d;
        float lh = log_hs[idx];
        float hs = fmaxf(expf(lh), HS_MIN);
        float lhc = fmaxf(lh, LOG_HS_MIN);
        float wv = kw[idx] - lsew[d];
        w[idx] = wv;
        c3[idx] = wv - lhc;
        ihs[idx] = 1.f / hs;
    }
}

// ---------------- K2: main KDE + inverse + term ----------------
__global__ __launch_bounds__(256) void k_main(const float* __restrict__ x,
                                              const float* __restrict__ dp,
                                              const float* __restrict__ w,
                                              const float* __restrict__ c3,
                                              const float* __restrict__ ihs,
                                              float* __restrict__ Y,
                                              float* __restrict__ T) {
    unsigned t = blockIdx.x * 256u + threadIdx.x;   // t < B*D exactly
    unsigned b = t / DD;
    unsigned d = t - b * DD;
    float xv = x[t];
    float m1 = -INFINITY, s1 = 0.f;
    float m2 = -INFINITY, s2 = 0.f;
    float m3 = -INFINITY, s3 = 0.f;
    for (int n = 0; n < NP; ++n) {
        unsigned idx = n * DD + d;
        float u = (dp[idx] - xv) * ihs[idx];
        float e = expf(-fabsf(u));
        float l1p = log1pf(e);
        float sp = fmaxf(u, 0.f) + l1p;
        float wv = w[idx];
        float a1 = wv - sp;
        float a2 = fminf(u, 0.f) - l1p + wv;
        float a3 = u - 2.f * sp + c3[idx];
        float nm;
        nm = fmaxf(m1, a1); s1 = s1 * expf(m1 - nm) + expf(a1 - nm); m1 = nm;
        nm = fmaxf(m2, a2); s2 = s2 * expf(m2 - nm) + expf(a2 - nm); m2 = nm;
        nm = fmaxf(m3, a3); s3 = s3 * expf(m3 - nm) + expf(a3 - nm); m3 = nm;
    }
    float log_cdf = m1 + logf(s1);
    float log_sf  = m2 + logf(s2);
    float log_pdf = m3 + logf(s3);

    // Log-space mask classification (cdf+sf == 1 exactly for the
    // weight-normalized logistic KDE, so cdf >= 1-5e-8  <=>  log_sf <= log(5e-8)).
    // Avoids the f32 cancellation at cdf ~ 1 that flips branches vs the f64 ref.
    bool right = (log_sf  <= LOG_MB);
    bool left  = (log_cdf <= LOG_MB);

    float inv, lgd;
    if (right) {
        float t2 = -2.f * log_sf;
        inv = sqrtf(t2);
        lgd = 0.5f * logf(t2) - log_sf;
    } else if (left) {
        float t2 = -2.f * log_cdf;
        inv = -sqrtf(t2);
        lgd = 0.5f * logf(t2) - log_cdf;
    } else {
        inv = (float)ndtri_logs(log_cdf, log_sf);
        lgd = -0.5f * inv * inv + NEG_HALF_LOG_2PI;
    }
    Y[t] = inv;
    T[t] = log_pdf - lgd;
}

// ---------------- K3: log_det reduction ----------------
__global__ __launch_bounds__(256) void k_logdet(const float* __restrict__ T,
                                                const float* __restrict__ ld_in,
                                                float* __restrict__ out) {
    __shared__ float red[4];
    int b = blockIdx.x;
    float s = 0.f;
    for (int d = threadIdx.x; d < DD; d += 256) s += T[b * DD + d];
    s = blockReduce256(s, red);
    if (threadIdx.x == 0) out[BB * DD + b] = ld_in[b] + s;
}

// ---------------- K4: normalize reflector rows ----------------
__global__ __launch_bounds__(256) void k_vn(const float* __restrict__ vs,
                                            float* __restrict__ vn) {
    __shared__ float red[4];
    int i = blockIdx.x;
    float ss = 0.f;
    for (int j = threadIdx.x; j < DD; j += 256) {
        float v = vs[i * DD + j];
        ss += v * v;
    }
    ss = blockReduce256(ss, red);
    float inorm = 1.f / sqrtf(ss);
    for (int j = threadIdx.x; j < DD; j += 256)
        vn[i * DD + j] = vs[i * DD + j] * inorm;
}

// ---------------- K5: Gram of each 16-reflector window ----------------
__global__ __launch_bounds__(256) void k_gram(const float* __restrict__ vn,
                                              float* __restrict__ G) {
    int wi = blockIdx.x;
    int t = threadIdx.x;
    int k = t >> 4, i = t & 15;
    const float4* a = (const float4*)(vn + (wi * W + k) * DD);
    const float4* b = (const float4*)(vn + (wi * W + i) * DD);
    float s = 0.f;
    for (int j = 0; j < DD / 4; ++j) {
        float4 av = a[j], bv = b[j];
        s += av.x * bv.x + av.y * bv.y + av.z * bv.z + av.w * bv.w;
    }
    G[wi * 256 + k * 16 + i] = s;   // G[w][k][i] = v_k . v_i
}

// ---------------- K6: apply 784 Householder reflections, windowed WY ----------------
__global__ __launch_bounds__(256) void k_house(const float* __restrict__ Yin,
                                               const float* __restrict__ VN,
                                               const float* __restrict__ G,
                                               float* __restrict__ out) {
    __shared__ float red[4 * W];
    __shared__ float s2s[W];
    int b = blockIdx.x;
    int tid = threadIdx.x;
    int lane = tid & 63;
    int wv = tid >> 6;
    bool has3 = (tid < DD - 3 * 256);   // 16 threads own a 4th element
    float y0 = Yin[b * DD + tid];
    float y1 = Yin[b * DD + tid + 256];
    float y2 = Yin[b * DD + tid + 512];
    float y3 = has3 ? Yin[b * DD + tid + 768] : 0.f;

    for (int wi = 0; wi < NW; ++wi) {
        // G column for this lane (only lanes<16 of wave 0 use it)
        float Gcol[W];
        #pragma unroll
        for (int k = 0; k < W; ++k)
            Gcol[k] = (tid < W) ? G[wi * 256 + k * 16 + tid] : 0.f;

        // load the window's 16 reflector rows at this thread's j's
        float v0[W], v1[W], v2[W], v3[W];
        #pragma unroll
        for (int r = 0; r < W; ++r) {
            const float* vr = VN + (wi * W + r) * DD;
            v0[r] = vr[tid];
            v1[r] = vr[tid + 256];
            v2[r] = vr[tid + 512];
            v3[r] = has3 ? vr[tid + 768] : 0.f;
        }

        // partial dots q_r against current (un-updated) y
        float p[W];
        #pragma unroll
        for (int r = 0; r < W; ++r)
            p[r] = y0 * v0[r] + y1 * v1[r] + y2 * v2[r] + y3 * v3[r];

        // wave butterfly reduce (all lanes end with the wave total)
        #pragma unroll
        for (int r = 0; r < W; ++r) {
            #pragma unroll
            for (int off = 32; off; off >>= 1)
                p[r] += __shfl_xor(p[r], off, 64);
        }
        // lane l keeps p[l]  (static selection, no dynamic register index)
        float mine = p[0];
        #pragma unroll
        for (int r = 1; r < W; ++r)
            if (lane == r) mine = p[r];
        if (lane < W) red[wv * W + lane] = mine;
        __syncthreads();

        // wave 0: cross-wave sum + forward substitution
        //   s_r = q_r - 2 * sum_{k<r} G[k][r] * s_k
        if (wv == 0) {
            float acc = 0.f;
            if (lane < W)
                acc = red[lane] + red[W + lane] + red[2 * W + lane] + red[3 * W + lane];
            #pragma unroll
            for (int k = 0; k < W; ++k) {
                float sk = __shfl(acc, k, 64);
                if (lane > k) acc -= 2.f * Gcol[k] * sk;
            }
            if (lane < W) s2s[lane] = 2.f * acc;
        }
        __syncthreads();

        // rank-16 update of y
        #pragma unroll
        for (int r = 0; r < W; ++r) {
            float s2 = s2s[r];
            y0 -= s2 * v0[r];
            y1 -= s2 * v1[r];
            y2 -= s2 * v2[r];
            y3 -= s2 * v3[r];
        }
        __syncthreads();   // protect red/s2s before next window's writes
    }

    out[b * DD + tid]       = y0;
    out[b * DD + tid + 256] = y1;
    out[b * DD + tid + 512] = y2;
    if (has3) out[b * DD + tid + 768] = y3;
}

// ---------------- launch ----------------
extern "C" void kernel_launch(void* const* d_in, const int* in_sizes, int n_in,
                              void* d_out, int out_size, void* d_ws, size_t ws_size,
                              hipStream_t stream) {
    const float* x      = (const float*)d_in[0];   // [B,D]
    const float* ld_in  = (const float*)d_in[1];   // [B]
    const float* dp     = (const float*)d_in[2];   // [N,D]
    const float* log_hs = (const float*)d_in[3];   // [N,D]
    const float* kw     = (const float*)d_in[4];   // [N,D]
    const float* vs     = (const float*)d_in[5];   // [D,D]
    float* out = (float*)d_out;                    // x_out [B,D] then log_det [B]

    float* ws   = (float*)d_ws;
    float* lsew = ws;                         // 784 (pad to 1024)
    float* w    = ws + 1024;                  // N*D
    float* c3   = w + NP * DD;                // N*D
    float* ihs  = c3 + NP * DD;               // N*D
    float* Y    = ihs + NP * DD;              // B*D
    float* T    = Y + BB * DD;                // B*D
    float* VN   = T + BB * DD;                // D*D
    float* G    = VN + DD * DD;               // NW*256

    k_lsew<<<(DD + 255) / 256, 256, 0, stream>>>(kw, lsew);
    k_prep<<<NP, 256, 0, stream>>>(kw, log_hs, lsew, w, c3, ihs);
    k_main<<<(BB * DD) / 256, 256, 0, stream>>>(x, dp, w, c3, ihs, Y, T);
    k_logdet<<<BB, 256, 0, stream>>>(T, ld_in, out);
    k_vn<<<DD, 256, 0, stream>>>(vs, VN);
    k_gram<<<NW, 256, 0, stream>>>(VN, G);
    k_house<<<BB, 256, 0, stream>>>(Y, VN, G, out);
}

// Round 3
// 394.892 us; speedup vs baseline: 1.5155x; 1.5155x over previous
//
#include <hip/hip_runtime.h>
#include <math.h>

#define NP 256   // datapoints
#define BB 128   // batch
#define DD 784   // dims
#define HS_MIN 1e-7f
#define LOG_HS_MIN -16.11809565095832f   // log(1e-7)
#define LOG_MB -16.811242831518264f      // log(5e-8) — mask bound in log space
#define NEG_HALF_LOG_2PI -0.9189385332046727f
#define W 16     // householder window
#define NW 49    // 784/16

// ---------------- ndtri (AS241, double poly) from log_cdf / log_sf ----------------
__device__ double ndtri_logs(float log_cdf_f, float log_sf_f) {
    double lp = (double)log_cdf_f;
    double ls = (double)log_sf_f;
    double p = (double)__expf(log_cdf_f);
    double q = p - 0.5;
    if (fabs(q) <= 0.425) {
        double r = 0.180625 - q * q;
        double num = (((((((2.5090809287301226727e3 * r + 3.3430575583588128105e4) * r
                         + 6.7265770927008700853e4) * r + 4.5921953931549871457e4) * r
                         + 1.3731693765509461125e4) * r + 1.9715909503065514427e3) * r
                         + 1.3314166789178437745e2) * r + 3.3871328727963666080e0);
        double den = (((((((5.2264952788528545610e3 * r + 2.8729085735721942674e4) * r
                         + 3.9307895800092710610e4) * r + 2.1213794301586595867e4) * r
                         + 5.3941960214247511077e3) * r + 6.8718700749205790830e2) * r
                         + 4.2313330701600911252e1) * r + 1.0);
        return q * num / den;
    }
    // tail: r = sqrt(-log(min(p,1-p))) straight from the log — no 1-p cancellation
    double r = (q < 0.0) ? sqrt(-lp) : sqrt(-ls);
    double v;
    if (r <= 5.0) {
        r -= 1.6;
        double num = (((((((7.74545014278341407640e-4 * r + 2.27238449892691845833e-2) * r
                         + 2.41780725177450611770e-1) * r + 1.27045825245236838258e0) * r
                         + 3.64784832476320460504e0) * r + 5.76949722146069140550e0) * r
                         + 4.63033784615654529590e0) * r + 1.42343711074968357734e0);
        double den = (((((((1.05075007164441684324e-9 * r + 5.47593808499534494600e-4) * r
                         + 1.51986665636164571966e-2) * r + 1.48103976427480074590e-1) * r
                         + 6.89767334985100004550e-1) * r + 1.67638483018380384940e0) * r
                         + 2.05319162663775882187e0) * r + 1.0);
        v = num / den;
    } else {
        r -= 5.0;
        double num = (((((((2.01033439929228813265e-7 * r + 2.71155556874348757815e-5) * r
                         + 1.24266094738807843860e-3) * r + 2.65321895265761230930e-2) * r
                         + 2.96560571828504891230e-1) * r + 1.78482653991729133580e0) * r
                         + 5.46378491116411436990e0) * r + 6.65790464350110377720e0);
        double den = (((((((2.04426310338993978564e-15 * r + 1.42151175831644588870e-7) * r
                         + 1.84631831751005468180e-5) * r + 7.86869131145613259100e-4) * r
                         + 1.48753612908506148525e-2) * r + 1.36929880922735805310e-1) * r
                         + 5.99832206555887937690e-1) * r + 1.0);
        v = num / den;
    }
    return (q < 0.0) ? -v : v;
}

// ---------------- K0: lsew[d] = logsumexp_n kde_weights[n,d] (block per d) ----------------
__global__ __launch_bounds__(256) void k_lsew(const float* __restrict__ kw,
                                              float* __restrict__ lsew) {
    __shared__ float red[4];
    int d = blockIdx.x;
    int n = threadIdx.x;          // NP == 256 == blockDim
    float a = kw[n * DD + d];
    float m = a;
    #pragma unroll
    for (int off = 32; off; off >>= 1) m = fmaxf(m, __shfl_xor(m, off, 64));
    if ((threadIdx.x & 63) == 0) red[threadIdx.x >> 6] = m;
    __syncthreads();
    m = fmaxf(fmaxf(red[0], red[1]), fmaxf(red[2], red[3]));
    __syncthreads();
    float e = __expf(a - m);
    #pragma unroll
    for (int off = 32; off; off >>= 1) e += __shfl_xor(e, off, 64);
    if ((threadIdx.x & 63) == 0) red[threadIdx.x >> 6] = e;
    __syncthreads();
    if (threadIdx.x == 0)
        lsew[d] = m + __logf(red[0] + red[1] + red[2] + red[3]);
}

// ---------------- K1: per-(n,d) precompute, packed float4 {dp, 1/hs, w, w-lhc} ----------------
__global__ __launch_bounds__(256) void k_prep(const float* __restrict__ kw,
                                              const float* __restrict__ log_hs,
                                              const float* __restrict__ dp,
                                              const float* __restrict__ lsew,
                                              float4* __restrict__ pk) {
    int n = blockIdx.x;
    for (int d = threadIdx.x; d < DD; d += 256) {
        int idx = n * DD + d;
        float lh = log_hs[idx];
        float hs = fmaxf(__expf(lh), HS_MIN);
        float lhc = fmaxf(lh, LOG_HS_MIN);
        float wv = kw[idx] - lsew[d];
        pk[idx] = make_float4(dp[idx], 1.f / hs, wv, wv - lhc);
    }
}

// ---------------- K2: main KDE + inverse + term ----------------
__global__ __launch_bounds__(256) void k_main(const float* __restrict__ x,
                                              const float4* __restrict__ pk,
                                              float* __restrict__ Y,
                                              float* __restrict__ T) {
    unsigned t = blockIdx.x * 256u + threadIdx.x;   // t < B*D exactly
    unsigned b = t / DD;
    unsigned d = t - b * DD;
    float xv = x[t];
    float m1 = -INFINITY, s1 = 0.f;
    float m2 = -INFINITY, s2 = 0.f;
    float m3 = -INFINITY, s3 = 0.f;
    for (int n = 0; n < NP; ++n) {
        float4 c = pk[n * DD + d];          // {dp, ihs, w, w-lhc}
        float u = (c.x - xv) * c.y;
        float e = __expf(-fabsf(u));
        float l1p = __logf(1.f + e);
        float sp = fmaxf(u, 0.f) + l1p;
        float a1 = c.z - sp;
        float a2 = fminf(u, 0.f) - l1p + c.z;
        float a3 = u - 2.f * sp + c.w;
        float nm;
        nm = fmaxf(m1, a1); s1 = s1 * __expf(m1 - nm) + __expf(a1 - nm); m1 = nm;
        nm = fmaxf(m2, a2); s2 = s2 * __expf(m2 - nm) + __expf(a2 - nm); m2 = nm;
        nm = fmaxf(m3, a3); s3 = s3 * __expf(m3 - nm) + __expf(a3 - nm); m3 = nm;
    }
    float log_cdf = m1 + __logf(s1);
    float log_sf  = m2 + __logf(s2);
    float log_pdf = m3 + __logf(s3);

    // log-space mask classification (no f32 cancellation at cdf ~ 1)
    bool right = (log_sf  <= LOG_MB);
    bool left  = (log_cdf <= LOG_MB);

    float inv, lgd;
    if (right) {
        float t2 = -2.f * log_sf;
        inv = sqrtf(t2);
        lgd = 0.5f * __logf(t2) - log_sf;
    } else if (left) {
        float t2 = -2.f * log_cdf;
        inv = -sqrtf(t2);
        lgd = 0.5f * __logf(t2) - log_cdf;
    } else {
        inv = (float)ndtri_logs(log_cdf, log_sf);
        lgd = -0.5f * inv * inv + NEG_HALF_LOG_2PI;
    }
    Y[t] = inv;
    T[t] = log_pdf - lgd;
}

// ---------------- K3: log_det reduction ----------------
__global__ __launch_bounds__(256) void k_logdet(const float* __restrict__ T,
                                                const float* __restrict__ ld_in,
                                                float* __restrict__ out) {
    __shared__ float red[4];
    int b = blockIdx.x;
    float s = 0.f;
    for (int d = threadIdx.x; d < DD; d += 256) s += T[b * DD + d];
    #pragma unroll
    for (int off = 32; off; off >>= 1) s += __shfl_down(s, off, 64);
    if ((threadIdx.x & 63) == 0) red[threadIdx.x >> 6] = s;
    __syncthreads();
    if (threadIdx.x == 0) out[BB * DD + b] = ld_in[b] + red[0] + red[1] + red[2] + red[3];
}

// ---------------- K4: normalize reflector rows ----------------
__global__ __launch_bounds__(256) void k_vn(const float* __restrict__ vs,
                                            float* __restrict__ vn) {
    __shared__ float red[4];
    int i = blockIdx.x;
    float ss = 0.f;
    for (int j = threadIdx.x; j < DD; j += 256) {
        float v = vs[i * DD + j];
        ss += v * v;
    }
    #pragma unroll
    for (int off = 32; off; off >>= 1) ss += __shfl_down(ss, off, 64);
    if ((threadIdx.x & 63) == 0) red[threadIdx.x >> 6] = ss;
    __syncthreads();
    float inorm = rsqrtf(red[0] + red[1] + red[2] + red[3]);
    for (int j = threadIdx.x; j < DD; j += 256)
        vn[i * DD + j] = vs[i * DD + j] * inorm;
}

// ---------------- K5: Gram of each 16-reflector window ----------------
__global__ __launch_bounds__(256) void k_gram(const float* __restrict__ vn,
                                              float* __restrict__ G) {
    int wi = blockIdx.x;
    int t = threadIdx.x;
    int k = t >> 4, i = t & 15;
    const float4* a = (const float4*)(vn + (wi * W + k) * DD);
    const float4* b = (const float4*)(vn + (wi * W + i) * DD);
    float s = 0.f;
    for (int j = 0; j < DD / 4; ++j) {
        float4 av = a[j], bv = b[j];
        s += av.x * bv.x + av.y * bv.y + av.z * bv.z + av.w * bv.w;
    }
    G[wi * 256 + k * 16 + i] = s;   // G[w][k][i] = v_k . v_i
}

// ---------------- K6: windowed-WY Householder chain, register double-buffer ----------------
// Thread t < 196 owns 4 consecutive y elements (784 = 4*196). Window's 16 V rows
// live in registers (float4 each); next window prefetched into the alternate buffer
// while current computes. __launch_bounds__(256,1): grid=128 < #CUs, so occupancy
// is irrelevant — let the allocator keep ~180 floats live (round 2's 76-VGPR cap
// forced V to be re-fetched from global inside the update loop: 253us latency-bound).
__device__ __forceinline__ void house_step(int wi, int tid, int lane, int wv, bool act, int j,
                                           bool prefetch,
                                           float4& y, float4* cur, float4* nxt,
                                           const float* __restrict__ VN,
                                           const float* __restrict__ G,
                                           float* red, float* s2s) {
    if (prefetch) {
        #pragma unroll
        for (int r = 0; r < W; ++r)
            nxt[r] = act ? *(const float4*)(VN + ((wi + 1) * W + r) * DD + j)
                         : make_float4(0.f, 0.f, 0.f, 0.f);
    }
    // G column for the forward substitution (only wave0 lanes<16 consume)
    float Gcol[W];
    #pragma unroll
    for (int k = 0; k < W; ++k)
        Gcol[k] = (tid < W) ? G[wi * 256 + k * 16 + tid] : 0.f;

    // partial dots q_r against current y
    float p[W];
    #pragma unroll
    for (int r = 0; r < W; ++r)
        p[r] = y.x * cur[r].x + y.y * cur[r].y + y.z * cur[r].z + y.w * cur[r].w;

    // in-wave butterfly
    #pragma unroll
    for (int r = 0; r < W; ++r) {
        #pragma unroll
        for (int off = 32; off; off >>= 1)
            p[r] += __shfl_xor(p[r], off, 64);
    }
    float mine = p[0];
    #pragma unroll
    for (int r = 1; r < W; ++r)
        if (lane == r) mine = p[r];
    if (lane < W) red[wv * W + lane] = mine;
    __syncthreads();

    // wave 0: cross-wave sum + forward substitution s_r = q_r - 2 sum_{k<r} G[k][r] s_k
    if (wv == 0) {
        float acc = 0.f;
        if (lane < W)
            acc = red[lane] + red[W + lane] + red[2 * W + lane] + red[3 * W + lane];
        #pragma unroll
        for (int k = 0; k < W; ++k) {
            float sk = __shfl(acc, k, 64);
            if (lane > k) acc -= 2.f * Gcol[k] * sk;
        }
        if (lane < W) s2s[lane] = 2.f * acc;
    }
    __syncthreads();

    // rank-16 update
    #pragma unroll
    for (int r = 0; r < W; ++r) {
        float s2 = s2s[r];
        y.x -= s2 * cur[r].x;
        y.y -= s2 * cur[r].y;
        y.z -= s2 * cur[r].z;
        y.w -= s2 * cur[r].w;
    }
    __syncthreads();
}

__global__ __launch_bounds__(256, 1) void k_house(const float* __restrict__ Yin,
                                                  const float* __restrict__ VN,
                                                  const float* __restrict__ G,
                                                  float* __restrict__ out) {
    __shared__ float red[4 * W];
    __shared__ float s2s[W];
    const int b = blockIdx.x;
    const int tid = threadIdx.x;
    const int lane = tid & 63;
    const int wv = tid >> 6;
    const bool act = (tid < DD / 4);     // 196 active threads
    const int j = 4 * tid;

    float4 y = act ? *(const float4*)(Yin + b * DD + j) : make_float4(0.f, 0.f, 0.f, 0.f);

    float4 A[W], Bf[W];
    #pragma unroll
    for (int r = 0; r < W; ++r)
        A[r] = act ? *(const float4*)(VN + r * DD + j) : make_float4(0.f, 0.f, 0.f, 0.f);

    // NW = 49: 24 double-buffered pairs + final window from A
    for (int wi = 0; wi < NW - 1; wi += 2) {
        house_step(wi,     tid, lane, wv, act, j, true, y, A, Bf, VN, G, red, s2s);
        house_step(wi + 1, tid, lane, wv, act, j, true, y, Bf, A, VN, G, red, s2s);
    }
    house_step(NW - 1, tid, lane, wv, act, j, false, y, A, Bf, VN, G, red, s2s);

    if (act) *(float4*)(out + b * DD + j) = y;
}

// ---------------- launch ----------------
extern "C" void kernel_launch(void* const* d_in, const int* in_sizes, int n_in,
                              void* d_out, int out_size, void* d_ws, size_t ws_size,
                              hipStream_t stream) {
    const float* x      = (const float*)d_in[0];   // [B,D]
    const float* ld_in  = (const float*)d_in[1];   // [B]
    const float* dp     = (const float*)d_in[2];   // [N,D]
    const float* log_hs = (const float*)d_in[3];   // [N,D]
    const float* kw     = (const float*)d_in[4];   // [N,D]
    const float* vs     = (const float*)d_in[5];   // [D,D]
    float* out = (float*)d_out;                    // x_out [B,D] then log_det [B]

    float* ws   = (float*)d_ws;
    float* lsew = ws;                         // 784 (pad to 1024)
    float4* pk  = (float4*)(ws + 1024);       // N*D float4
    float* Y    = ws + 1024 + NP * DD * 4;    // B*D
    float* T    = Y + BB * DD;                // B*D
    float* VN   = T + BB * DD;                // D*D
    float* G    = VN + DD * DD;               // NW*256

    k_lsew<<<DD, 256, 0, stream>>>(kw, lsew);
    k_prep<<<NP, 256, 0, stream>>>(kw, log_hs, dp, lsew, pk);
    k_main<<<(BB * DD) / 256, 256, 0, stream>>>(x, pk, Y, T);
    k_logdet<<<BB, 256, 0, stream>>>(T, ld_in, out);
    k_vn<<<DD, 256, 0, stream>>>(vs, VN);
    k_gram<<<NW, 256, 0, stream>>>(VN, G);
    k_house<<<BB, 256, 0, stream>>>(Y, VN, G, out);
}